// Round 8
// baseline (571.618 us; speedup 1.0000x reference)
//
#include <hip/hip_runtime.h>
#include <hip/hip_bf16.h>

#define N_NODES 50000
#define N_EDGES 1600000
#define IN_DIM 1024
#define HID 128
#define AGG_WAVES 6144          // 1536 blocks x 4 waves = 24 waves/CU at launch_bounds(256,6)

typedef __bf16 bf16x8 __attribute__((ext_vector_type(8)));
typedef float f32x4 __attribute__((ext_vector_type(4)));
typedef __bf16 bf16x4 __attribute__((ext_vector_type(4)));

// bf16-pair (packed in uint) -> 2 floats (features 2l = low, 2l+1 = high)
__device__ __forceinline__ float2 bf2f(unsigned u) {
    return make_float2(__uint_as_float(u << 16), __uint_as_float(u & 0xffff0000u));
}
__device__ __forceinline__ float lrelu(float v) { return v > 0.f ? v : 0.2f * v; }
// fp16 bits (in low 16 of arg) -> float
__device__ __forceinline__ float f16tof(unsigned bits) {
    return (float)__builtin_bit_cast(_Float16, (unsigned short)bits);
}

// ---------------------------------------------------------------- prep: zero deg/out + W^T->bf16
__global__ void prep_kernel(const float* __restrict__ W, __bf16* __restrict__ wt,
                            int* __restrict__ deg, float* __restrict__ out, int out_n) {
    int i = blockIdx.x * 256 + threadIdx.x;       // grid covers 131072
    if (i < N_NODES) deg[i] = 0;
    if (i < out_n) out[i] = 0.0f;
    if (i < HID * IN_DIM) {
        int n = i >> 10, k = i & 1023;
        wt[i] = (__bf16)W[(size_t)k * HID + n];
    }
}

// ---------------------------------------------------------------- GEMM h = x @ W (bf16 MFMA)
// BM=128 x BN=128 (full HID), BK=32, 391 blocks. Each wave owns 32 rows (2
// A-frags): per K-step 16 MFMA vs 10 ds_read_b128 (was 8 vs 9 at BM=64), and
// each B-frag feeds 2 MFMAs -- double the compute per staging/barrier quantum.
// Double-buffered LDS (41KB -> 3 blocks/CU), register prefetch of next tile.
// Epilogue: fused att dots + h2 repack through the dead LDS (coalesced 8B
// stores; R5 showed 4.6x write amplification without it).
__global__ __launch_bounds__(256) void gemm_kernel(const float* __restrict__ x,
                                                   const __bf16* __restrict__ wt,
                                                   __bf16* __restrict__ h2,
                                                   const float* __restrict__ att_s,
                                                   const float* __restrict__ att_d,
                                                   float* __restrict__ o_as,
                                                   float* __restrict__ o_ad,
                                                   float* __restrict__ o_ps) {
    __shared__ union {
        struct { __bf16 xa[2][128][40]; __bf16 wb[2][128][40]; } s;  // 41 KB
        __bf16 ep[128][132];                                         // 33.8 KB (epilogue)
    } u;
    const int t = threadIdx.x;
    const int m0 = blockIdx.x * 128;
    const int wid = t >> 6, lane = t & 63;
    const int lm = lane & 15, q8 = (lane >> 4) * 8;
    const int rw0 = wid * 32;                     // wave's 32-row band

    float4 xs_reg[4];
    uint2  ws_reg[4];

    auto stage_regs = [&](int k0) {
#pragma unroll
        for (int l = 0; l < 4; ++l) {
            int f = t + l * 256;
            int row = f >> 3, kq = f & 7;
            int gr = m0 + row;
            float4 v = make_float4(0.f, 0.f, 0.f, 0.f);
            if (gr < N_NODES)
                v = *(const float4*)(x + (size_t)gr * IN_DIM + k0 + kq * 4);
            xs_reg[l] = v;
        }
#pragma unroll
        for (int l = 0; l < 4; ++l) {
            int f = t + l * 256;
            int n = f >> 3, c = f & 7;
            ws_reg[l] = *(const uint2*)(wt + (size_t)n * IN_DIM + k0 + c * 4);
        }
    };
    auto regs_to_lds = [&](int b) {
#pragma unroll
        for (int l = 0; l < 4; ++l) {
            int f = t + l * 256;
            int row = f >> 3, kq = f & 7;
            bf16x4 v;
            v[0] = (__bf16)xs_reg[l].x; v[1] = (__bf16)xs_reg[l].y;
            v[2] = (__bf16)xs_reg[l].z; v[3] = (__bf16)xs_reg[l].w;
            *(bf16x4*)&u.s.xa[b][row][kq * 4] = v;
        }
#pragma unroll
        for (int l = 0; l < 4; ++l) {
            int f = t + l * 256;
            int n = f >> 3, c = f & 7;
            *(uint2*)&u.s.wb[b][n][c * 4] = ws_reg[l];
        }
    };

    f32x4 acc[2][8] = {};
    stage_regs(0);
    regs_to_lds(0);
    __syncthreads();
    for (int it = 0; it < 32; ++it) {
        const int cur = it & 1;
        if (it + 1 < 32) stage_regs((it + 1) * 32);   // global loads in flight during MFMA
        bf16x8 af0 = *(const bf16x8*)&u.s.xa[cur][rw0 + lm][q8];
        bf16x8 af1 = *(const bf16x8*)&u.s.xa[cur][rw0 + 16 + lm][q8];
#pragma unroll
        for (int ct = 0; ct < 8; ++ct) {
            bf16x8 bfr = *(const bf16x8*)&u.s.wb[cur][ct * 16 + lm][q8];
            acc[0][ct] = __builtin_amdgcn_mfma_f32_16x16x32_bf16(af0, bfr, acc[0][ct], 0, 0, 0);
            acc[1][ct] = __builtin_amdgcn_mfma_f32_16x16x32_bf16(af1, bfr, acc[1][ct], 0, 0, 0);
        }
        if (it + 1 < 32) {
            regs_to_lds(cur ^ 1);     // write OTHER buffer: no read-write conflict
            __syncthreads();          // make writes visible for next iter's reads
        }
    }
    // epilogue part 1: fused att dots (C/D layout col=lane&15, row=(lane>>4)*4+reg)
    const int quad = lane >> 4;
    float attsf[8], attdf[8];
#pragma unroll
    for (int ct = 0; ct < 8; ++ct) {
        attsf[ct] = att_s[ct * 16 + lm];
        attdf[ct] = att_d[ct * 16 + lm];
    }
#pragma unroll
    for (int a = 0; a < 2; ++a) {
#pragma unroll
        for (int reg = 0; reg < 4; ++reg) {
            int row = m0 + rw0 + a * 16 + quad * 4 + reg;
            float ps = 0.f, pd = 0.f;
#pragma unroll
            for (int ct = 0; ct < 8; ++ct) {
                float v = acc[a][ct][reg];
                ps = fmaf(v, attsf[ct], ps);
                pd = fmaf(v, attdf[ct], pd);
            }
#pragma unroll
            for (int o = 8; o; o >>= 1) {
                ps += __shfl_xor(ps, o);
                pd += __shfl_xor(pd, o);
            }
            if (row < N_NODES && lm == 0) {
                o_as[row] = ps; o_ad[row] = pd;
                o_ps[row] = __expf(lrelu(ps + pd));   // self-loop weight, precomputed
            }
        }
    }
    // epilogue part 2: h2 via LDS repack -> coalesced 8B stores.
    __syncthreads();              // all waves done with xa/wb before aliasing
#pragma unroll
    for (int a = 0; a < 2; ++a)
#pragma unroll
    for (int reg = 0; reg < 4; ++reg) {
        int lrow = rw0 + a * 16 + quad * 4 + reg;
#pragma unroll
        for (int ct = 0; ct < 8; ++ct)
            u.ep[lrow][ct * 16 + lm] = (__bf16)acc[a][ct][reg];
    }
    __syncthreads();
    {
        int lr = t >> 1, half = t & 1;           // row 0..127, 64-feature half
        int grow = m0 + lr;
        if (grow < N_NODES) {
            uint2* dst = (uint2*)(h2 + (size_t)grow * HID + half * 64);
            const __bf16* srcp = &u.ep[lr][half * 64];
#pragma unroll
            for (int j = 0; j < 16; ++j)
                dst[j] = *(const uint2*)(srcp + j * 4);
        }
    }
}

// ---------------------------------------------------------------- CSR build
// SINGLE atomic pass over edges: hist's atomicAdd also records each edge's slot
// within its dst row (epos); scatter is atomic-free.
__global__ void hist_kernel(const int* __restrict__ ei, int* __restrict__ deg,
                            int* __restrict__ epos) {
    int e = blockIdx.x * 256 + threadIdx.x;
    if (e < N_EDGES) epos[e] = atomicAdd(&deg[ei[N_EDGES + e]], 1);
}

// FUSED single-block exclusive scan (replaces scan1+scan2+scan3: 3 launches +
// scan2's serial 49-iteration dependent-load chain). 1024 threads x 49 elems:
// register-local scan + wave shfl scan + 16-partial block scan via LDS.
__global__ __launch_bounds__(1024) void scan_kernel(const int* __restrict__ deg,
                                                    int* __restrict__ rowstart) {
    const int t = threadIdx.x, lane = t & 63, w = t >> 6;   // 16 waves
    const int base = t * 49;                                // 1024*49 = 50176 >= N
    int v[49]; int s = 0;
#pragma unroll
    for (int j = 0; j < 49; ++j) {
        int idx = base + j;
        v[j] = (idx < N_NODES) ? deg[idx] : 0;
        s += v[j];
    }
    int inc = s;                                  // wave-inclusive scan of s
    for (int o = 1; o < 64; o <<= 1) {
        int u2 = __shfl_up(inc, o);
        if (lane >= o) inc += u2;
    }
    __shared__ int wsum[16];
    if (lane == 63) wsum[w] = inc;
    __syncthreads();
    int woff = 0;
    for (int i = 0; i < w; ++i) woff += wsum[i];  // <=15 LDS reads
    int run = woff + inc - s;                     // exclusive prefix for this thread
#pragma unroll
    for (int j = 0; j < 49; ++j) {
        int idx = base + j;
        if (idx < N_NODES) { rowstart[idx] = run; run += v[j]; }
    }
    if (t == 1023) rowstart[N_NODES] = run;       // grand total
}

// scatter (atomic-free): slot = rowstart[d] + epos[e]. PACKED payload:
// u16 src | fp16 pe (4B/edge), pe = exp(lrelu(a_src[s]+a_dst[d])) precomputed
// so the hot aggregate loop does zero transcendental work. src < 65536 OK;
// pe in [~e^-1, ~e^3], well inside fp16; 2^-11 rel err << bf16 noise floor.
__global__ void scatter_kernel(const int* __restrict__ ei, const int* __restrict__ rowstart,
                               const int* __restrict__ epos, unsigned* __restrict__ csrp,
                               const float* __restrict__ a_src, const float* __restrict__ a_dst) {
    int e = blockIdx.x * 256 + threadIdx.x;
    if (e >= N_EDGES) return;
    int s = ei[e], d = ei[N_EDGES + e];
    float pe = __expf(lrelu(a_src[s] + a_dst[d]));
    unsigned short hb = __builtin_bit_cast(unsigned short, (_Float16)pe);
    csrp[rowstart[d] + epos[e]] = (unsigned)s | ((unsigned)hb << 16);
}

// ---------------------------------------------------------------- aggregate+pool
// R0's measured-best shape at its measured-best register budget: lane owns
// features {2l,2l+1}; 64-edge chunk per lane; 16-deep register batch of
// shfl-broadcast packed (src|pe) -> 16 independent row-gathers in flight.
// launch_bounds(256,6): VGPR cap 85 (bounds(256,8) spilled -- R3 lesson).
// Denominator accumulated redundantly per-lane from the broadcast pe.
__global__ __launch_bounds__(256, 6) void aggregate_kernel(
    const unsigned* __restrict__ h2u, const float* __restrict__ pself_a,
    const int* __restrict__ rowstart, const unsigned* __restrict__ csrp,
    const float* __restrict__ bias, const int* __restrict__ batch,
    float* __restrict__ out) {
    const int wid = threadIdx.x >> 6, lane = threadIdx.x & 63;
    const int w = blockIdx.x * 4 + wid;
    const int q = N_NODES / AGG_WAVES;
    const int r = N_NODES - q * AGG_WAVES;
    int n0 = w * q + (w < r ? w : r);
    int n1 = n0 + q + (w < r ? 1 : 0);
    const float b0 = bias[2 * lane], b1 = bias[2 * lane + 1];

    int gcur = -1;
    float m0 = 0.f, m1 = 0.f;
    for (int n = n0; n < n1; ++n) {
        int rs = rowstart[n], re = rowstart[n + 1];
        float psf = pself_a[n];
        float2 hv = bf2f(h2u[((unsigned)n << 6) | (unsigned)lane]);
        float denom = psf;
        float2 acc = make_float2(psf * hv.x, psf * hv.y);
        for (int base = rs; base < re; base += 64) {
            int cnt = re - base; if (cnt > 64) cnt = 64;
            unsigned sp = 0u;                 // src=0, pe=0 for invalid lanes
            if (base + lane < re) sp = csrp[base + lane];
            for (int e = 0; e < cnt; e += 16) {
                unsigned bb[16], uu[16];
#pragma unroll
                for (int i = 0; i < 16; ++i) {
                    bb[i] = (unsigned)__shfl((int)sp, e + i);
                    uu[i] = h2u[((bb[i] & 0xffffu) << 6) | (unsigned)lane];
                }
#pragma unroll
                for (int i = 0; i < 16; ++i) {
                    float2 g = bf2f(uu[i]);
                    float p = f16tof(bb[i] >> 16);
                    acc.x = fmaf(p, g.x, acc.x);
                    acc.y = fmaf(p, g.y, acc.y);
                    denom += p;               // every lane sums every pe: no shfl reduce
                }
            }
        }
        float inv = 1.0f / denom;
        float o0 = fmaxf(fmaf(acc.x, inv, b0), 0.0f);
        float o1 = fmaxf(fmaf(acc.y, inv, b1), 0.0f);
        int g = batch[n];
        if (g != gcur) {
            if (gcur >= 0) {
                unsigned* outp = (unsigned*)(out + (size_t)gcur * HID);
                atomicMax(&outp[2 * lane], __float_as_uint(m0));
                atomicMax(&outp[2 * lane + 1], __float_as_uint(m1));
            }
            gcur = g; m0 = o0; m1 = o1;
        } else {
            m0 = fmaxf(m0, o0); m1 = fmaxf(m1, o1);
        }
    }
    if (gcur >= 0) {
        unsigned* outp = (unsigned*)(out + (size_t)gcur * HID);
        atomicMax(&outp[2 * lane], __float_as_uint(m0));
        atomicMax(&outp[2 * lane + 1], __float_as_uint(m1));
    }
}

// ---------------------------------------------------------------- launch
extern "C" void kernel_launch(void* const* d_in, const int* in_sizes, int n_in,
                              void* d_out, int out_size, void* d_ws, size_t ws_size,
                              hipStream_t stream) {
    const float* x     = (const float*)d_in[0];
    const float* W     = (const float*)d_in[1];
    const float* att_s = (const float*)d_in[2];
    const float* att_d = (const float*)d_in[3];
    const float* bias  = (const float*)d_in[4];
    const int*   ei    = (const int*)d_in[5];
    const int*   batch = (const int*)d_in[6];
    float*       out   = (float*)d_out;

    char* ws = (char*)d_ws;
    size_t off = 0;
    auto alloc = [&](size_t bytes) -> void* {
        void* p = ws + off;
        off += (bytes + 255) & ~(size_t)255;
        return p;
    };
    __bf16*   h2       = (__bf16*)alloc((size_t)N_NODES * HID * 2);
    __bf16*   wt       = (__bf16*)alloc((size_t)HID * IN_DIM * 2);
    float*    a_src    = (float*)alloc((size_t)N_NODES * 4);
    float*    a_dst    = (float*)alloc((size_t)N_NODES * 4);
    float*    pself    = (float*)alloc((size_t)N_NODES * 4);
    int*      deg      = (int*)alloc((size_t)N_NODES * 4);
    int*      rowstart = (int*)alloc((size_t)(N_NODES + 1) * 4);
    int*      epos     = (int*)alloc((size_t)N_EDGES * 4);
    unsigned* csrp     = (unsigned*)alloc((size_t)N_EDGES * 4);
    (void)ws_size; (void)in_sizes; (void)n_in;

    hipLaunchKernelGGL(prep_kernel, dim3(512), dim3(256), 0, stream,
                       W, wt, deg, out, out_size);
    hipLaunchKernelGGL(gemm_kernel, dim3((N_NODES + 127) / 128), dim3(256), 0, stream,
                       x, wt, h2, att_s, att_d, a_src, a_dst, pself);
    hipLaunchKernelGGL(hist_kernel, dim3((N_EDGES + 255) / 256), dim3(256), 0, stream,
                       ei, deg, epos);
    hipLaunchKernelGGL(scan_kernel, dim3(1), dim3(1024), 0, stream, deg, rowstart);
    hipLaunchKernelGGL(scatter_kernel, dim3((N_EDGES + 255) / 256), dim3(256), 0, stream,
                       ei, rowstart, epos, csrp, a_src, a_dst);
    hipLaunchKernelGGL(aggregate_kernel, dim3(AGG_WAVES / 4), dim3(256), 0, stream,
                       (const unsigned*)h2, pself, rowstart, csrp, bias, batch, out);
}